// Round 3
// baseline (157.495 us; speedup 1.0000x reference)
//
#include <hip/hip_runtime.h>
#include <math.h>

#define NW   12
#define DIM  4096
#define TPB  256

// global LDS swizzle: XOR stored-address bits 6-9 into bits 0-3.
// Applied identically on every psi write and read (bijective -> consistent).
__device__ __forceinline__ int swz(int a) { return a ^ ((a >> 6) & 15); }

// complex multiply
__device__ __forceinline__ float2 cmulq(float2 a, float2 b) {
    return make_float2(fmaf(a.x, b.x, -a.y * b.y), fmaf(a.x, b.y, a.y * b.x));
}

// RY on register bit B (0..3 of the 16-amp register file). Pure VALU.
template<int B>
__device__ __forceinline__ void ry_reg(float2* r, float c, float s) {
#pragma unroll
    for (int p = 0; p < 8; ++p) {
        const int i0 = ((p >> B) << (B + 1)) | (p & ((1 << B) - 1));
        const int i1 = i0 | (1 << B);
        const float2 a = r[i0], b = r[i1];
        r[i0].x = fmaf(-s, b.x, c * a.x);
        r[i0].y = fmaf(-s, b.y, c * a.y);
        r[i1].x = fmaf( s, a.x, c * b.x);
        r[i1].y = fmaf( s, a.y, c * b.y);
    }
}

__global__ __launch_bounds__(TPB, 4)
void qmnist_kernel(const float* __restrict__ x,  const float* __restrict__ W1,
                   const float* __restrict__ b1, const float* __restrict__ ryp,
                   const float* __restrict__ rzp, const float* __restrict__ W2,
                   const float* __restrict__ b2, float* __restrict__ out) {
    // Exactly 32 KiB LDS. Small arrays alias the front (state lives in
    // registers whenever they are live; barriers order every transition).
    __shared__ float2 psi[DIM];
    float* smf  = (float*)psi;
    float* wred = smf;        // 48 floats
    float* encc = smf + 48;   // 12
    float* encs = smf + 60;   // 12
    float* zfin = smf + 72;   // 12

    const int tid  = threadIdx.x;
    const int blk  = blockIdx.x;
    const int lane = tid & 63;
    const int wave = tid >> 6;
    const int l03  = lane & 15;      // lane bits 0-3
    const int l45  = lane & 48;      // lane bits 4-5 (in place)

    // ---------------- phase 0: feat = x[blk] @ W1^T + b1 -> encoding angles
    float acc[NW];
#pragma unroll
    for (int w = 0; w < NW; ++w) acc[w] = 0.f;
    if (tid < 196) {                      // 784 = 196 float4
        const float4 xv = ((const float4*)(x + (size_t)blk * 784))[tid];
#pragma unroll
        for (int w = 0; w < NW; ++w) {
            const float4 wv = ((const float4*)(W1 + w * 784))[tid];
            acc[w] = fmaf(xv.x, wv.x, fmaf(xv.y, wv.y, fmaf(xv.z, wv.z, xv.w * wv.w)));
        }
    }
#pragma unroll
    for (int w = 0; w < NW; ++w) {
        float v = acc[w];
        v += __shfl_down(v, 32);
        v += __shfl_down(v, 16);
        v += __shfl_down(v, 8);
        v += __shfl_down(v, 4);
        v += __shfl_down(v, 2);
        v += __shfl_down(v, 1);
        if (lane == 0) wred[wave * NW + w] = v;
    }
    __syncthreads();
    if (tid < NW) {
        float feat = wred[tid] + wred[NW + tid] + wred[2 * NW + tid] + wred[3 * NW + tid] + b1[tid];
        float a = tanhf(feat) * 3.14159265358979323846f;
        float h = 0.5f * a;
        encc[tid] = cosf(h);
        encs[tid] = sinf(h);
    }
    __syncthreads();

    // ---------------- init product state into REGISTERS.
    // amp index y = k*256 + tid; bit b of y <-> wire (11-b). bits 0..7 = tid, 8..11 = k.
    float hi = 1.f;
#pragma unroll
    for (int b = 0; b < 8; ++b)
        hi *= ((tid >> b) & 1) ? encs[11 - b] : encc[11 - b];
    float2 r[16];
#pragma unroll
    for (int k = 0; k < 16; ++k) {
        float f = hi;
        f *= (k & 1) ? encs[3] : encc[3];
        f *= (k & 2) ? encs[2] : encc[2];
        f *= (k & 4) ? encs[1] : encc[1];
        f *= (k & 8) ? encs[0] : encc[0];
        r[k] = make_float2(f, 0.f);
    }

    // ---------------- variational params.
    // Layer = RY on all 12 wires, RZ on all 12 wires (folds to a popcount
    // phase, bit-permutation invariant), then CNOT staircase.
    const float ry = ryp[0], rz = rzp[0];
    const float c = cosf(0.5f * ry), s = sinf(0.5f * ry);
    const int pcT = __popc(tid);
    float2 q[5];                                   // q[j] = cis(rz*(popc(tid)+j-6))
#pragma unroll
    for (int j = 0; j < 5; ++j) {
        const float ang = rz * (float)(pcT + j - 6);
        q[j] = make_float2(cosf(ang), sinf(ang));
    }

    const int baseA  = wave << 10;                       // wave-local 1024-amp region
    const int rbaseA = baseA | (l03 << 6) | l45;         // RT-A read base

    for (int layer = 0; layer < 3; ++layer) {
        __syncthreads();                // prior block-wide psi reads done

        // G1: gate globals {8,9,10,11} (reg bits) -- canonical layout
        ry_reg<0>(r, c, s); ry_reg<1>(r, c, s); ry_reg<2>(r, c, s); ry_reg<3>(r, c, s);

        // --- RT-A: swap positions {0,1,2,3} <-> {8,9,10,11}.
        // Wave-local addressing (bijective block-wide); plain barrier ordering —
        // the asm-waitcnt variant caused the private array to spill to scratch.
#pragma unroll
        for (int k = 0; k < 16; ++k)
            psi[baseA | (k << 6) | (lane ^ k)] = r[k];   // = swz(baseA|k<<6|lane)
        __syncthreads();
#pragma unroll
        for (int k = 0; k < 16; ++k)
            r[k] = psi[rbaseA | (k ^ l03)];              // = swz(read addr)

        // G2: gate globals {0,1,2,3} (now reg bits)
        ry_reg<0>(r, c, s); ry_reg<1>(r, c, s); ry_reg<2>(r, c, s); ry_reg<3>(r, c, s);

        // --- RT-BC (barriered): swap positions {4,5,6,7} <-> {8,9,10,11}
        __syncthreads();                // all waves' RT-A reads done
#pragma unroll
        for (int k = 0; k < 16; ++k)
            psi[swz((k << 8) | tid)] = r[k];
        __syncthreads();
#pragma unroll
        for (int k = 0; k < 16; ++k) {
            const int a = l03 | ((k & 3) << 4) | ((k >> 2) << 6) | (l45 << 4) | (wave << 10);
            r[k] = psi[swz(a)];
        }

        // G3: gate globals {4,5,6,7} (now reg bits)
        ry_reg<0>(r, c, s); ry_reg<1>(r, c, s); ry_reg<2>(r, c, s); ry_reg<3>(r, c, s);

        // fold of all 12 RZ gates: phase by popcount (layout-invariant)
#pragma unroll
        for (int k = 0; k < 16; ++k)
            r[k] = cmulq(r[k], q[__popc(k)]);

        // --- RT-D (barriered): CNOT staircase new[y] = old[y ^ (y>>1)], fused
        // with layout restore. Current layout is rotl4: stored(y) = rotl4(y).
        __syncthreads();                // all RT-BC reads done
#pragma unroll
        for (int k = 0; k < 16; ++k)
            psi[swz((k << 8) | tid)] = r[k];
        __syncthreads();
#pragma unroll
        for (int k = 0; k < 16; ++k) {
            const int y = (k << 8) | tid;
            const int g = y ^ (y >> 1);
            const int a = ((g >> 8) | (g << 4)) & 4095;  // rotl4(g)
            r[k] = psi[swz(a)];
        }
    }
    __syncthreads();                    // all psi reads done before aliasing reuse

    // ---------------- measure <Z_w> from registers (canonical layout)
    float t_total = 0.f, s3 = 0.f, s2 = 0.f, s1 = 0.f, s0 = 0.f;
#pragma unroll
    for (int k = 0; k < 16; ++k) {
        const float pp = fmaf(r[k].x, r[k].x, r[k].y * r[k].y);
        t_total += pp;
        if (k & 1) s3 += pp;   // bit 8  -> wire 3
        if (k & 2) s2 += pp;   // bit 9  -> wire 2
        if (k & 4) s1 += pp;   // bit 10 -> wire 1
        if (k & 8) s0 += pp;   // bit 11 -> wire 0
    }
    float contrib[NW];
    contrib[3] = t_total - 2.f * s3;
    contrib[2] = t_total - 2.f * s2;
    contrib[1] = t_total - 2.f * s1;
    contrib[0] = t_total - 2.f * s0;
#pragma unroll
    for (int b = 0; b < 8; ++b) {
        const int w = 11 - b;                       // wires 11..4 from tid bits 0..7
        contrib[w] = ((tid >> b) & 1) ? -t_total : t_total;
    }
#pragma unroll
    for (int w = 0; w < NW; ++w) {
        float v = contrib[w];
        v += __shfl_down(v, 32);
        v += __shfl_down(v, 16);
        v += __shfl_down(v, 8);
        v += __shfl_down(v, 4);
        v += __shfl_down(v, 2);
        v += __shfl_down(v, 1);
        if (lane == 0) wred[wave * NW + w] = v;
    }
    __syncthreads();
    if (tid < NW)
        zfin[tid] = wred[tid] + wred[NW + tid] + wred[2 * NW + tid] + wred[3 * NW + tid];
    __syncthreads();

    // ---------------- head: out = z @ W2^T + b2
    if (tid < 10) {
        float o = b2[tid];
#pragma unroll
        for (int w = 0; w < NW; ++w)
            o = fmaf(zfin[w], W2[tid * NW + w], o);
        out[(size_t)blk * 10 + tid] = o;
    }
}

extern "C" void kernel_launch(void* const* d_in, const int* in_sizes, int n_in,
                              void* d_out, int out_size, void* d_ws, size_t ws_size,
                              hipStream_t stream) {
    const float* x   = (const float*)d_in[0];
    const float* W1  = (const float*)d_in[1];
    const float* b1  = (const float*)d_in[2];
    const float* ry  = (const float*)d_in[3];
    const float* rz  = (const float*)d_in[4];
    const float* W2  = (const float*)d_in[5];
    const float* b2  = (const float*)d_in[6];
    float* out = (float*)d_out;

    const int batch = in_sizes[0] / 784;   // 2048
    qmnist_kernel<<<batch, TPB, 0, stream>>>(x, W1, b1, ry, rz, W2, b2, out);
}

// Round 4
// 118.626 us; speedup vs baseline: 1.3277x; 1.3277x over previous
//
#include <hip/hip_runtime.h>
#include <math.h>

#define NW   12
#define DIM  4096
#define TPB  256

// complex multiply
__device__ __forceinline__ float2 cmulq(float2 a, float2 b) {
    return make_float2(fmaf(a.x, b.x, -a.y * b.y), fmaf(a.x, b.y, a.y * b.x));
}

// DPP lane exchange (VALU, no LDS pipe). CTRL: 0xB1=XOR1, 0x4E=XOR2, 0x128=row_ror:8(=XOR8).
template<int CTRL>
__device__ __forceinline__ float fdpp(float v) {
    union { float f; int i; } u, w;
    u.f = v;
    w.i = __builtin_amdgcn_update_dpp(0, u.i, CTRL, 0xF, 0xF, false);
    return w.f;
}

// RY on register bit B (0..3 of the 16-amp register file). Pure VALU.
template<int B>
__device__ __forceinline__ void ry_reg(float2* r, float c, float s) {
#pragma unroll
    for (int p = 0; p < 8; ++p) {
        const int i0 = ((p >> B) << (B + 1)) | (p & ((1 << B) - 1));
        const int i1 = i0 | (1 << B);
        const float2 a = r[i0], b = r[i1];
        r[i0].x = fmaf(-s, b.x, c * a.x);
        r[i0].y = fmaf(-s, b.y, c * a.y);
        r[i1].x = fmaf( s, a.x, c * b.x);
        r[i1].y = fmaf( s, a.y, c * b.y);
    }
}

// RY via DPP partner exchange on a lane bit; sp = +s if lane bit set else -s.
template<int CTRL>
__device__ __forceinline__ void ry_dpp(float2* r, float c, float sp) {
#pragma unroll
    for (int k = 0; k < 16; ++k) {
        const float px = fdpp<CTRL>(r[k].x);
        const float py = fdpp<CTRL>(r[k].y);
        r[k].x = fmaf(sp, px, c * r[k].x);
        r[k].y = fmaf(sp, py, c * r[k].y);
    }
}

__global__ __launch_bounds__(TPB, 4)
void qmnist_kernel(const float* __restrict__ x,  const float* __restrict__ W1,
                   const float* __restrict__ b1, const float* __restrict__ ryp,
                   const float* __restrict__ rzp, const float* __restrict__ W2,
                   const float* __restrict__ b2, float* __restrict__ out) {
    // Exactly 32 KiB LDS. Small arrays alias the front (state lives in
    // registers whenever they are live; barriers order every transition).
    __shared__ float2 psi[DIM];
    float* smf  = (float*)psi;
    float* wred = smf;        // 48 floats
    float* encc = smf + 48;   // 12
    float* encs = smf + 60;   // 12
    float* zfin = smf + 72;   // 12

    const int tid  = threadIdx.x;
    const int blk  = blockIdx.x;
    const int lane = tid & 63;
    const int wave = tid >> 6;

    // ---------------- phase 0: feat = x[blk] @ W1^T + b1 -> encoding angles
    float acc[NW];
#pragma unroll
    for (int w = 0; w < NW; ++w) acc[w] = 0.f;
    if (tid < 196) {                      // 784 = 196 float4
        const float4 xv = ((const float4*)(x + (size_t)blk * 784))[tid];
#pragma unroll
        for (int w = 0; w < NW; ++w) {
            const float4 wv = ((const float4*)(W1 + w * 784))[tid];
            acc[w] = fmaf(xv.x, wv.x, fmaf(xv.y, wv.y, fmaf(xv.z, wv.z, xv.w * wv.w)));
        }
    }
#pragma unroll
    for (int w = 0; w < NW; ++w) {
        float v = acc[w];
        v += __shfl_down(v, 32);
        v += __shfl_down(v, 16);
        v += __shfl_down(v, 8);
        v += __shfl_down(v, 4);
        v += __shfl_down(v, 2);
        v += __shfl_down(v, 1);
        if (lane == 0) wred[wave * NW + w] = v;
    }
    __syncthreads();
    if (tid < NW) {
        float feat = wred[tid] + wred[NW + tid] + wred[2 * NW + tid] + wred[3 * NW + tid] + b1[tid];
        float a = tanhf(feat) * 3.14159265358979323846f;
        float h = 0.5f * a;
        encc[tid] = cosf(h);
        encs[tid] = sinf(h);
    }
    __syncthreads();

    // ---------------- init product state into REGISTERS.
    // amp index y = (k<<8)|tid; bit b of y <-> wire (11-b). bits 0..7 = tid, 8..11 = k.
    float hi = 1.f;
#pragma unroll
    for (int b = 0; b < 8; ++b)
        hi *= ((tid >> b) & 1) ? encs[11 - b] : encc[11 - b];
    float2 r[16];
#pragma unroll
    for (int k = 0; k < 16; ++k) {
        float f = hi;
        f *= (k & 1) ? encs[3] : encc[3];
        f *= (k & 2) ? encs[2] : encc[2];
        f *= (k & 4) ? encs[1] : encc[1];
        f *= (k & 8) ? encs[0] : encc[0];
        r[k] = make_float2(f, 0.f);
    }

    // ---------------- variational params.
    // Layer = RY on all 12 positions, RZ on all 12 (folds to popcount phase,
    // layout-invariant), then CNOT staircase new[y] = old[y ^ (y>>1)].
    const float ry = ryp[0], rz = rzp[0];
    const float c = cosf(0.5f * ry), s = sinf(0.5f * ry);
    const int pcT = __popc(tid);
    float2 q[5];                                   // q[j] = cis(rz*(popc(tid)+j-6))
#pragma unroll
    for (int j = 0; j < 5; ++j) {
        const float ang = rz * (float)(pcT + j - 6);
        q[j] = make_float2(cosf(ang), sinf(ang));
    }

    // per-lane signed s for the lane-exchange RY gates (position = lane bit)
    const float s0p = (lane & 1)  ? s : -s;   // position 0, XOR1  (quad_perm)
    const float s1p = (lane & 2)  ? s : -s;   // position 1, XOR2  (quad_perm)
    const float s3p = (lane & 8)  ? s : -s;   // position 3, XOR8  (row_ror:8)
    const float s5p = (lane & 32) ? s : -s;   // position 5, XOR32 (shfl)

    // RT-A / RT-C separable addressing: ONE base VGPR + compile-time immediates.
    // idx'(k',thr) = l0|l1<<1|l3<<3|l5<<5 | l2<<8|l4<<9|wave<<10 | k'0<<2|k'1<<4|k'2<<6|k'3<<7
    // (bijective; read/write low4 = {l0,l1,k'0,l3} -> 2-way bank alias = free)
    const int baseA = (lane & 43) | ((lane & 4) << 6) | ((lane & 16) << 5) | (wave << 10);
    const int gt    = tid ^ (tid >> 1);            // CNOT gather base (bit7 = tid7)

    for (int layer = 0; layer < 3; ++layer) {
        __syncthreads();                // prior psi readers done

        // RY on positions 8-11 (register bits), canonical layout
        ry_reg<0>(r, c, s); ry_reg<1>(r, c, s); ry_reg<2>(r, c, s); ry_reg<3>(r, c, s);

        // RY on positions 0,1,3 via DPP (VALU), position 5 via shfl_xor
        ry_dpp<0xB1>(r, c, s0p);        // XOR1
        ry_dpp<0x4E>(r, c, s1p);        // XOR2
        ry_dpp<0x128>(r, c, s3p);       // XOR8 within row of 16
#pragma unroll
        for (int k = 0; k < 16; ++k) {
            const float px = __shfl_xor(r[k].x, 32, 64);
            const float py = __shfl_xor(r[k].y, 32, 64);
            r[k].x = fmaf(s5p, px, c * r[k].x);
            r[k].y = fmaf(s5p, py, c * r[k].y);
        }

        // --- RT-A: canonical store, permuted read -> k' holds positions {2,4,6,7}
#pragma unroll
        for (int k = 0; k < 16; ++k)
            psi[(k << 8) | tid] = r[k];                 // base tid + imm 2048k
        __syncthreads();
#pragma unroll
        for (int k = 0; k < 16; ++k)
            r[k] = psi[baseA | ((k & 1) << 2) | ((k & 2) << 3) | ((k & 4) << 4) | ((k & 8) << 4)];

        // RY on positions 2,4,6,7 (now register bits)
        ry_reg<0>(r, c, s); ry_reg<1>(r, c, s); ry_reg<2>(r, c, s); ry_reg<3>(r, c, s);

        // fold of all 12 RZ gates: phase by popcount (layout-invariant)
#pragma unroll
        for (int k = 0; k < 16; ++k)
            r[k] = cmulq(r[k], q[__popc(k)]);

        // --- RT-C: store canonically (same base+imm map), CNOT gather back to L0
        __syncthreads();                // all RT-A reads done
#pragma unroll
        for (int k = 0; k < 16; ++k)
            psi[baseA | ((k & 1) << 2) | ((k & 2) << 3) | ((k & 4) << 4) | ((k & 8) << 4)] = r[k];
        __syncthreads();
#pragma unroll
        for (int k = 0; k < 16; ++k) {
            const int g = ((k & 1) ? (gt ^ 128) : gt) | (((k ^ (k >> 1)) & 15) << 8);
            r[k] = psi[g];              // two bases + Gray immediate; lane-bijective banks
        }
    }
    __syncthreads();                    // all psi reads done before aliasing reuse

    // ---------------- measure <Z_w> from registers (canonical layout)
    float t_total = 0.f, s3 = 0.f, s2 = 0.f, s1 = 0.f, s0 = 0.f;
#pragma unroll
    for (int k = 0; k < 16; ++k) {
        const float pp = fmaf(r[k].x, r[k].x, r[k].y * r[k].y);
        t_total += pp;
        if (k & 1) s3 += pp;   // bit 8  -> wire 3
        if (k & 2) s2 += pp;   // bit 9  -> wire 2
        if (k & 4) s1 += pp;   // bit 10 -> wire 1
        if (k & 8) s0 += pp;   // bit 11 -> wire 0
    }
    float contrib[NW];
    contrib[3] = t_total - 2.f * s3;
    contrib[2] = t_total - 2.f * s2;
    contrib[1] = t_total - 2.f * s1;
    contrib[0] = t_total - 2.f * s0;
#pragma unroll
    for (int b = 0; b < 8; ++b) {
        const int w = 11 - b;                       // wires 11..4 from tid bits 0..7
        contrib[w] = ((tid >> b) & 1) ? -t_total : t_total;
    }
#pragma unroll
    for (int w = 0; w < NW; ++w) {
        float v = contrib[w];
        v += __shfl_down(v, 32);
        v += __shfl_down(v, 16);
        v += __shfl_down(v, 8);
        v += __shfl_down(v, 4);
        v += __shfl_down(v, 2);
        v += __shfl_down(v, 1);
        if (lane == 0) wred[wave * NW + w] = v;
    }
    __syncthreads();
    if (tid < NW)
        zfin[tid] = wred[tid] + wred[NW + tid] + wred[2 * NW + tid] + wred[3 * NW + tid];
    __syncthreads();

    // ---------------- head: out = z @ W2^T + b2
    if (tid < 10) {
        float o = b2[tid];
#pragma unroll
        for (int w = 0; w < NW; ++w)
            o = fmaf(zfin[w], W2[tid * NW + w], o);
        out[(size_t)blk * 10 + tid] = o;
    }
}

extern "C" void kernel_launch(void* const* d_in, const int* in_sizes, int n_in,
                              void* d_out, int out_size, void* d_ws, size_t ws_size,
                              hipStream_t stream) {
    const float* x   = (const float*)d_in[0];
    const float* W1  = (const float*)d_in[1];
    const float* b1  = (const float*)d_in[2];
    const float* ry  = (const float*)d_in[3];
    const float* rz  = (const float*)d_in[4];
    const float* W2  = (const float*)d_in[5];
    const float* b2  = (const float*)d_in[6];
    float* out = (float*)d_out;

    const int batch = in_sizes[0] / 784;   // 2048
    qmnist_kernel<<<batch, TPB, 0, stream>>>(x, W1, b1, ry, rz, W2, b2, out);
}